// Round 14
// baseline (221.551 us; speedup 1.0000x reference)
//
#include <hip/hip_runtime.h>
#include <cstdint>
#include <cstddef>
#include <type_traits>

// ---------------------------------------------------------------------------
// FlashSparseAttention: X->QKV proj -> RoPE -> causal GQA flash attn -> O proj
// B=2 S=2048 H=2048 NH=16 NKV=4 HD=128, fp32 in/out, bf16 MFMA internally.
// R14: R13 + race fix. R13's single-barrier attn loop let wave A's
//      global_load_lds overwrite a slot wave Z was still reading (lgkmcnt(0)
//      drains only own-wave reads). Two-barrier protocol: BARRIER -> stage
//      (other slot) -> counted vmcnt -> BARRIER -> compute -> lgkmcnt(0).
//      This also explains R12's absmax creep (same latent race).
// ---------------------------------------------------------------------------

typedef __bf16 bf16x8 __attribute__((ext_vector_type(8)));
typedef float f32x4 __attribute__((ext_vector_type(4)));
typedef float f32x16 __attribute__((ext_vector_type(16)));
typedef int i32x4 __attribute__((ext_vector_type(4)));

#define DEVFN static __device__ __forceinline__

constexpr int Bc = 2, Sc = 2048, Hc = 2048, NHc = 16, NKVc = 4, HDc = 128;
constexpr float SM_SCALE = 0.08838834764831845f;   // 1/sqrt(128)
constexpr float QSCALE = 0.127517431f;             // SM_SCALE * log2(e)
constexpr float DEFER_THR = 11.0f;                 // ~8 nats in log2 domain

DEVFN unsigned short f2bf(float f) {
  __bf16 h = (__bf16)f;
  return __builtin_bit_cast(unsigned short, h);
}
DEVFN float bf2f(unsigned short s) { return __uint_as_float(((unsigned)s) << 16); }

DEVFN unsigned cvtpk(float lo, float hi) {
  unsigned r;
  asm("v_cvt_pk_bf16_f32 %0, %1, %2" : "=v"(r) : "v"(lo), "v"(hi));
  return r;
}
DEVFN void pswap(unsigned& x, unsigned& y) {
  asm("v_permlane32_swap_b32 %0, %1" : "+v"(x), "+v"(y));
}

DEVFN f32x16 mfma32(bf16x8 a, bf16x8 b, f32x16 c) {
  return __builtin_amdgcn_mfma_f32_32x32x16_bf16(a, b, c, 0, 0, 0);
}
DEVFN f32x4 mfma16(bf16x8 a, bf16x8 b, f32x4 c) {
  return __builtin_amdgcn_mfma_f32_16x16x32_bf16(a, b, c, 0, 0, 0);
}

DEVFN void gload_lds16(const void* g, void* l) {
  __builtin_amdgcn_global_load_lds(
      (const __attribute__((address_space(1))) unsigned int*)g,
      (__attribute__((address_space(3))) unsigned int*)l, 16, 0, 0);
}

#define BAR() __builtin_amdgcn_s_barrier()

// ---------------- fp32 -> bf16 conversion (vectorized x4) ------------------
__global__ __launch_bounds__(256) void cvt_kernel(const float* __restrict__ in,
                                                  unsigned short* __restrict__ out,
                                                  int n4) {
  int i = blockIdx.x * 256 + threadIdx.x;
  if (i >= n4) return;
  float4 v = reinterpret_cast<const float4*>(in)[i];
  ushort4 o;
  o.x = f2bf(v.x); o.y = f2bf(v.y); o.z = f2bf(v.z); o.w = f2bf(v.w);
  reinterpret_cast<ushort4*>(out)[i] = o;
}

// ---------------- fused weight conversion (Wq|Wk|Wv -> Wqkv, Wo -> Wob) ----
__global__ __launch_bounds__(256) void cvt_weights(const float* __restrict__ Wq,
                                                   const float* __restrict__ Wk,
                                                   const float* __restrict__ Wv,
                                                   const float* __restrict__ Wo,
                                                   unsigned short* __restrict__ Wqkv,
                                                   unsigned short* __restrict__ Wob) {
  const int i = blockIdx.x * 256 + threadIdx.x;  // float4 index, total 2621440
  const float* src;
  unsigned short* dst;
  int off;
  if (i < 1048576) { src = Wq; dst = Wqkv; off = i; }
  else if (i < 1310720) { src = Wk; dst = Wqkv + 4194304; off = i - 1048576; }
  else if (i < 1572864) { src = Wv; dst = Wqkv + 5242880; off = i - 1310720; }
  else { src = Wo; dst = Wob; off = i - 1572864; }
  float4 v = reinterpret_cast<const float4*>(src)[off];
  ushort4 o;
  o.x = f2bf(v.x); o.y = f2bf(v.y); o.z = f2bf(v.z); o.w = f2bf(v.w);
  reinterpret_cast<ushort4*>(dst)[off] = o;
}

// ---------------- RoPE cos/sin table: [s][d] d in 0..63, f32 ---------------
__global__ __launch_bounds__(256) void rope_table(float* __restrict__ cosT,
                                                  float* __restrict__ sinT) {
  const int i = blockIdx.x * 256 + threadIdx.x;  // 131072 = 2048*64
  const int s = i >> 6, d = i & 63;
  const float inv = exp2f(-0.2076205059304601f * (float)d);  // 10000^(-d/64)
  float sn, c;
  sincosf((float)s * inv, &sn, &c);
  cosT[i] = c;
  sinT[i] = sn;
}

// ---------------- 2-phase counted NT GEMM (BM=256, BK=64, grid 256) ---------
template <int BN, int MODE>
__global__ __launch_bounds__(512, 2) void gemm2p(const unsigned short* __restrict__ A,
                                                 const unsigned short* __restrict__ Bw,
                                                 void* __restrict__ o0,
                                                 void* __restrict__ o1,
                                                 void* __restrict__ o2) {
  constexpr int NT = 32;                       // K/64
  constexpr int NREP = BN / 64;                // 3 or 2
  constexpr int NBL = (BN == 192) ? 2 : 1;     // B loads per K-half
  constexpr int BBH = NBL * 8192;              // B K-half bytes (padded)
  constexpr int BUFSZ = 32768 + 2 * BBH;       // 65536 / 49152
  constexpr int G = 2 + NBL;                   // loads per K-half group
  __shared__ __align__(16) char smem[2 * BUFSZ];

  const int tid = threadIdx.x;
  const int w = tid >> 6, l = tid & 63;
  const int wm = w >> 2, wn = w & 3;

  const int wgid = (blockIdx.x & 7) * 32 + (blockIdx.x >> 3);
  const int bm = (wgid & 15) << 8;
  const int bn = (wgid >> 4) * BN;

  const int srow = tid >> 2;                                   // 0..127
  const int scb = (((tid & 3) ^ ((tid >> 3) & 3)) << 4);
  const char* Agp = (const char*)A + ((size_t)(bm + srow) << 12) + scb;
  const char* Bgp = (const char*)Bw + ((size_t)(bn + srow) << 12) + scb;

  auto stageG = [&](int BB, int kk, int kt) {    // one K-half group (A + B)
#pragma unroll
    for (int c = 0; c < 2; c++)
      gload_lds16(Agp + ((size_t)(c * 128) << 12) + kt * 128 + kk * 64,
                  smem + BB + kk * 16384 + c * 8192 + tid * 16);
#pragma unroll
    for (int c = 0; c < NBL; c++)
      gload_lds16(Bgp + ((size_t)(c * 128) << 12) + kt * 128 + kk * 64,
                  smem + BB + 32768 + kk * BBH + c * 8192 + tid * 16);
  };

  const int gA = (((l >> 4) ^ ((l >> 1) & 3)) << 4);
  const int laneA = (wm * 128 + (l & 15)) * 64 + gA;
  const int laneB = 32768 + (wn * (BN / 4) + (l & 15)) * 64 + gA;

  f32x4 acc[8][NREP];
#pragma unroll
  for (int m = 0; m < 8; m++)
#pragma unroll
    for (int n = 0; n < NREP; n++) acc[m][n] = f32x4{0.f, 0.f, 0.f, 0.f};

  stageG(0, 0, 0);
  stageG(0, 1, 0);
  stageG(BUFSZ, 0, 1);
  asm volatile("s_waitcnt vmcnt(%0)" ::"n"(2 * G) : "memory");
  BAR();

  auto phase = [&](int t, int kk, auto bufc) {
    constexpr int BB = decltype(bufc)::value;
    constexpr int BO = BB ^ BUFSZ;
    if (kk == 0) {
      if (t + 1 < NT) stageG(BO, 1, t + 1);
    } else {
      if (t + 2 < NT) stageG(BB, 0, t + 2);
    }
    bf16x8 af[8], bfr[NREP];
#pragma unroll
    for (int m = 0; m < 8; m++)
      af[m] = *(const bf16x8*)(smem + BB + kk * 16384 + laneA + m * 1024);
#pragma unroll
    for (int n = 0; n < NREP; n++)
      bfr[n] = *(const bf16x8*)(smem + BB + kk * BBH + laneB + n * 1024);
    __builtin_amdgcn_s_setprio(1);
#pragma unroll
    for (int m = 0; m < 8; m++)
#pragma unroll
      for (int n = 0; n < NREP; n++)
        acc[m][n] = mfma16(af[m], bfr[n], acc[m][n]);
    __builtin_amdgcn_s_setprio(0);
    if (kk == 0) {
      if (t + 1 < NT) { asm volatile("s_waitcnt vmcnt(%0)" ::"n"(2 * G) : "memory"); }
      else            { asm volatile("s_waitcnt vmcnt(0)" ::: "memory"); }
    } else {
      if (t + 2 < NT)      { asm volatile("s_waitcnt vmcnt(%0)" ::"n"(2 * G) : "memory"); }
      else if (t + 1 < NT) { asm volatile("s_waitcnt vmcnt(%0)" ::"n"(G) : "memory"); }
    }
    asm volatile("s_waitcnt lgkmcnt(0)" ::: "memory");
    BAR();
  };

  for (int t = 0; t < NT; t += 2) {
    phase(t, 0, std::integral_constant<int, 0>{});
    phase(t, 1, std::integral_constant<int, 0>{});
    phase(t + 1, 0, std::integral_constant<int, BUFSZ>{});
    phase(t + 1, 1, std::integral_constant<int, BUFSZ>{});
  }

#pragma unroll
  for (int m = 0; m < 8; m++) {
#pragma unroll
    for (int n = 0; n < NREP; n++) {
#pragma unroll
      for (int r = 0; r < 4; r++) {
        const int row = bm + wm * 128 + m * 16 + ((l >> 4) << 2) + r;
        const int col = bn + wn * (BN / 4) + n * 16 + (l & 15);
        const float v = acc[m][n][r];
        if (MODE == 1) {
          ((float*)o0)[(size_t)row * 2048 + col] = v;
        } else {
          const unsigned short q = f2bf(v);
          if (col < 2048) {
            ((unsigned short*)o0)[(size_t)row * 2048 + col] = q;
          } else if (col < 2560) {
            ((unsigned short*)o1)[(size_t)row * 512 + (col - 2048)] = q;
          } else {
            const int cv = col - 2560;
            ((unsigned short*)o2)[((size_t)(((row >> 11) * NKVc + (cv >> 7)) * HDc + (cv & 127)) << 11) +
                                  (row & 2047)] = q;
          }
        }
      }
    }
  }
}

// ---------------- K RoPE + relayout: raw[tok][kv*128+d] -> [b][kv][s][d] ----
__global__ __launch_bounds__(256) void rope_k(const unsigned short* __restrict__ raw,
                                              unsigned short* __restrict__ dst,
                                              const float* __restrict__ cosT,
                                              const float* __restrict__ sinT) {
  const int t = blockIdx.x * 256 + threadIdx.x;
  const int d = t & 63;
  const int h = (t >> 6) & 3;
  const int tok = t >> 8;
  const int b = tok >> 11, s = tok & 2047;
  const float c = cosT[(s << 6) + d];
  const float sn = sinT[(s << 6) + d];
  const size_t src = (size_t)tok * 512 + h * 128 + d;
  const float x0 = bf2f(raw[src]);
  const float x1 = bf2f(raw[src + 64]);
  const size_t db = ((size_t)(b * NKVc + h) * Sc + s) * HDc + d;
  dst[db] = f2bf(x0 * c - x1 * sn);
  dst[db + 64] = f2bf(x1 * c + x0 * sn);
}

// ---------------- causal GQA flash attention (R14: KVBLK=128, race-fixed) ---
// grid 256 = 8 groups (g = b*4+kvh, XCD-pinned) x 32 q-tiles (t, 64 rows).
// Block: 8 waves = 4 heads x 2 qsub; wave = 32 q-rows of one head.
// NIT = (t>>1)+1 <= 16 KV-128 iterations; LDS 2 x 64KB dbuf.
// Two-barrier protocol per iter (race-free slot reuse):
//   BAR -> stage(other slot, i+1) -> vmcnt(8) -> BAR -> compute -> lgkm(0).
__global__ __launch_bounds__(512, 2) void attn_kernel(const unsigned short* __restrict__ Qraw,
                                                      const unsigned short* __restrict__ Kr,
                                                      const unsigned short* __restrict__ Vt,
                                                      unsigned short* __restrict__ O,
                                                      const float* __restrict__ cosT,
                                                      const float* __restrict__ sinT) {
  __shared__ __align__(16) char smem[131072];

  const int tid = threadIdx.x, w = tid >> 6, l = tid & 63;
  const int lq = l & 31, lh = l >> 5;
  const int g = blockIdx.x & 7;                 // (b, kvh) group -> XCD
  const int t = blockIdx.x >> 3;                // 0..31 (64-row q-tile)
  const int b = g >> 2, kvh = g & 3;
  const int h = kvh * 4 + (w & 3), qsub = w >> 2;
  const int NIT = (t >> 1) + 1;                 // 1..16
  const int qpos = t * 64 + qsub * 32 + lq;

  const char* Kb = (const char*)(Kr + (size_t)(b * NKVc + kvh) * Sc * HDc);
  const char* Vb = (const char*)(Vt + (size_t)(b * NKVc + kvh) * HDc * Sc);

  // staging: 512 threads x 16B; K/V 128 rows x 256B each = 4 issues apiece
  const int srw = tid >> 4;                                 // 0..31
  const int scb = ((tid & 15) * 16) ^ ((srw & 7) << 4);     // pre-swizzled col
  auto stage = [&](int slot, int kt_) {
#pragma unroll
    for (int c = 0; c < 4; c++)
      gload_lds16(Kb + (size_t)(kt_ * 128 + c * 32 + srw) * 256 + scb,
                  smem + slot + c * 8192 + tid * 16);
#pragma unroll
    for (int c = 0; c < 4; c++)
      gload_lds16(Vb + (size_t)(c * 32 + srw) * 4096 + kt_ * 256 + scb,
                  smem + slot + 32768 + c * 8192 + tid * 16);
  };

  // read constants: row = base32*j + lq, 256B rows, swizzle (row&7)<<4
  const int swz = (l & 7) << 4;
  const int hi16 = lh << 4;
  int co[8];
#pragma unroll
  for (int kc = 0; kc < 8; kc++) co[kc] = (kc * 32 + hi16) ^ swz;
  const int rbase = lq * 256;

  // Q B-frags: col=q=lq, k = kc*16 + lh*8 + j; RoPE pairs (kc, kc+4)
  bf16x8 qf[8];
  {
    const int srow = qpos;
    const unsigned short* Qp = Qraw + ((size_t)(b * Sc + srow) << 11) + h * 128 + lh * 8;
#pragma unroll
    for (int kc = 0; kc < 4; kc++) {
      const bf16x8 vlo = *(const bf16x8*)(Qp + kc * 16);
      const bf16x8 vhi = *(const bf16x8*)(Qp + kc * 16 + 64);
      const float* cp = cosT + ((size_t)srow << 6) + kc * 16 + lh * 8;
      const float* sp = sinT + ((size_t)srow << 6) + kc * 16 + lh * 8;
      const float4 c0 = *(const float4*)cp, c1 = *(const float4*)(cp + 4);
      const float4 s0v = *(const float4*)sp, s1v = *(const float4*)(sp + 4);
      const float cs[8] = {c0.x, c0.y, c0.z, c0.w, c1.x, c1.y, c1.z, c1.w};
      const float ss[8] = {s0v.x, s0v.y, s0v.z, s0v.w, s1v.x, s1v.y, s1v.z, s1v.w};
#pragma unroll
      for (int j = 0; j < 8; j++) {
        const float xl = (float)vlo[j] * QSCALE;
        const float xh = (float)vhi[j] * QSCALE;
        qf[kc][j] = (__bf16)(xl * cs[j] - xh * ss[j]);
        qf[kc + 4][j] = (__bf16)(xh * cs[j] + xl * ss[j]);
      }
    }
  }

  f32x16 oacc[4];
#pragma unroll
  for (int d = 0; d < 4; d++)
#pragma unroll
    for (int r = 0; r < 16; r++) oacc[d][r] = 0.f;
  float m_run = -1e30f, sum_run = 0.f;

  stage(0, 0);

  auto iter = [&](int i, auto slotc) {
    constexpr int SLOT = decltype(slotc)::value;
    // barrier 1: all waves finished reading the slot we are about to refill
    __builtin_amdgcn_s_barrier();
    if (i + 1 < NIT) {
      stage(SLOT ^ 65536, i + 1);
      asm volatile("s_waitcnt vmcnt(8)" ::: "memory");
    } else {
      asm volatile("s_waitcnt vmcnt(0)" ::: "memory");
    }
    // barrier 2: every wave's current-slot loads have landed
    __builtin_amdgcn_s_barrier();

    // ---- S^T = K Q : four 32x32 blocks over kv 0..127 ----
    f32x16 s0, s1, s2, s3;
#pragma unroll
    for (int r = 0; r < 16; r++) { s0[r] = 0.f; s1[r] = 0.f; s2[r] = 0.f; s3[r] = 0.f; }
    __builtin_amdgcn_s_setprio(1);
#pragma unroll
    for (int kc = 0; kc < 8; kc++) {
      s0 = mfma32(*(const bf16x8*)(smem + SLOT + rbase + co[kc]), qf[kc], s0);
      s1 = mfma32(*(const bf16x8*)(smem + SLOT + 8192 + rbase + co[kc]), qf[kc], s1);
      s2 = mfma32(*(const bf16x8*)(smem + SLOT + 16384 + rbase + co[kc]), qf[kc], s2);
      s3 = mfma32(*(const bf16x8*)(smem + SLOT + 24576 + rbase + co[kc]), qf[kc], s3);
    }
    __builtin_amdgcn_s_setprio(0);

    if (i == NIT - 1) {                    // diagonal tile: causal mask
      const int kv0 = i * 128 + 4 * lh;
#pragma unroll
      for (int r = 0; r < 16; r++) {
        const int kvv = kv0 + (r & 3) + 8 * (r >> 2);
        if (kvv > qpos) s0[r] = -1e30f;
        if (kvv + 32 > qpos) s1[r] = -1e30f;
        if (kvv + 64 > qpos) s2[r] = -1e30f;
        if (kvv + 96 > qpos) s3[r] = -1e30f;
      }
    }

    // ---- online softmax (q = lane col; kv in regs + lane^32) ----
    float m0 = -1e30f, m1 = -1e30f, m2 = -1e30f, m3 = -1e30f;
#pragma unroll
    for (int r = 0; r < 4; r++) {
      m0 = fmaxf(m0, fmaxf(fmaxf(s0[4 * r], s0[4 * r + 1]), fmaxf(s0[4 * r + 2], s0[4 * r + 3])));
      m1 = fmaxf(m1, fmaxf(fmaxf(s1[4 * r], s1[4 * r + 1]), fmaxf(s1[4 * r + 2], s1[4 * r + 3])));
      m2 = fmaxf(m2, fmaxf(fmaxf(s2[4 * r], s2[4 * r + 1]), fmaxf(s2[4 * r + 2], s2[4 * r + 3])));
      m3 = fmaxf(m3, fmaxf(fmaxf(s3[4 * r], s3[4 * r + 1]), fmaxf(s3[4 * r + 2], s3[4 * r + 3])));
    }
    float mt = fmaxf(fmaxf(m0, m1), fmaxf(m2, m3));
    mt = fmaxf(mt, __shfl_xor(mt, 32));
    if (!__all(mt <= m_run + DEFER_THR)) {
      const float mn = fmaxf(m_run, mt);
      const float al = exp2f(m_run - mn);
      m_run = mn;
      sum_run *= al;
#pragma unroll
      for (int d = 0; d < 4; d++)
#pragma unroll
        for (int r = 0; r < 16; r++) oacc[d][r] *= al;
    }

    // ---- P = exp2(S - m) in place; accumulate sum ----
    float sA = 0.f, sB = 0.f, sC = 0.f, sD = 0.f;
#pragma unroll
    for (int r = 0; r < 16; r += 4) {
      s0[r] = exp2f(s0[r] - m_run);         sA += s0[r];
      s0[r + 1] = exp2f(s0[r + 1] - m_run); sB += s0[r + 1];
      s0[r + 2] = exp2f(s0[r + 2] - m_run); sC += s0[r + 2];
      s0[r + 3] = exp2f(s0[r + 3] - m_run); sD += s0[r + 3];
      s1[r] = exp2f(s1[r] - m_run);         sA += s1[r];
      s1[r + 1] = exp2f(s1[r + 1] - m_run); sB += s1[r + 1];
      s1[r + 2] = exp2f(s1[r + 2] - m_run); sC += s1[r + 2];
      s1[r + 3] = exp2f(s1[r + 3] - m_run); sD += s1[r + 3];
      s2[r] = exp2f(s2[r] - m_run);         sA += s2[r];
      s2[r + 1] = exp2f(s2[r + 1] - m_run); sB += s2[r + 1];
      s2[r + 2] = exp2f(s2[r + 2] - m_run); sC += s2[r + 2];
      s2[r + 3] = exp2f(s2[r + 3] - m_run); sD += s2[r + 3];
      s3[r] = exp2f(s3[r] - m_run);         sA += s3[r];
      s3[r + 1] = exp2f(s3[r + 1] - m_run); sB += s3[r + 1];
      s3[r + 2] = exp2f(s3[r + 2] - m_run); sC += s3[r + 2];
      s3[r + 3] = exp2f(s3[r + 3] - m_run); sD += s3[r + 3];
    }
    sum_run += (sA + sB) + (sC + sD);

    // ---- per kv-32 block: build 2 P^T frags, accumulate PV ----
    __builtin_amdgcn_s_setprio(1);
#define PV_BLOCK(SV, C0)                                                      \
    {                                                                         \
      bf16x8 pfA, pfB;                                                        \
      {                                                                       \
        unsigned a0 = cvtpk(SV[0], SV[1]), a2 = cvtpk(SV[4], SV[5]);          \
        unsigned a1 = cvtpk(SV[2], SV[3]), a3 = cvtpk(SV[6], SV[7]);          \
        pswap(a0, a2); pswap(a1, a3);                                         \
        i32x4 t4 = {(int)a0, (int)a1, (int)a2, (int)a3};                      \
        pfA = __builtin_bit_cast(bf16x8, t4);                                 \
      }                                                                       \
      {                                                                       \
        unsigned a0 = cvtpk(SV[8], SV[9]), a2 = cvtpk(SV[12], SV[13]);        \
        unsigned a1 = cvtpk(SV[10], SV[11]), a3 = cvtpk(SV[14], SV[15]);      \
        pswap(a0, a2); pswap(a1, a3);                                         \
        i32x4 t4 = {(int)a0, (int)a1, (int)a2, (int)a3};                      \
        pfB = __builtin_bit_cast(bf16x8, t4);                                 \
      }                                                                       \
      _Pragma("unroll")                                                       \
      for (int d = 0; d < 4; d++) {                                           \
        oacc[d] = mfma32(*(const bf16x8*)(smem + SLOT + 32768 + d * 8192 +    \
                                          rbase + co[C0]), pfA, oacc[d]);     \
        oacc[d] = mfma32(*(const bf16x8*)(smem + SLOT + 32768 + d * 8192 +    \
                                          rbase + co[C0 + 1]), pfB, oacc[d]); \
      }                                                                       \
    }
    PV_BLOCK(s0, 0)
    PV_BLOCK(s1, 2)
    PV_BLOCK(s2, 4)
    PV_BLOCK(s3, 6)
#undef PV_BLOCK
    __builtin_amdgcn_s_setprio(0);

    asm volatile("s_waitcnt lgkmcnt(0)" ::: "memory");  // own reads drained
  };

  for (int i = 0; i < NIT; i += 2) {
    iter(i, std::integral_constant<int, 0>{});
    if (i + 1 < NIT) iter(i + 1, std::integral_constant<int, 65536>{});
  }

  // epilogue: normalize, write O^T (lane q = col, d in regs)
  const float st = sum_run + __shfl_xor(sum_run, 32);
  const float rinv = 1.0f / st;
  unsigned short* Op = O + ((size_t)(b * Sc + qpos) << 11) + h * 128 + lh * 4;
#pragma unroll
  for (int d = 0; d < 4; d++) {
#pragma unroll
    for (int rq = 0; rq < 4; rq++) {
      uint2 u2;
      u2.x = cvtpk(oacc[d][4 * rq] * rinv, oacc[d][4 * rq + 1] * rinv);
      u2.y = cvtpk(oacc[d][4 * rq + 2] * rinv, oacc[d][4 * rq + 3] * rinv);
      *(uint2*)(Op + d * 32 + rq * 8) = u2;
    }
  }
}

// ---------------------------------------------------------------------------
extern "C" void kernel_launch(void* const* d_in, const int* in_sizes, int n_in,
                              void* d_out, int out_size, void* d_ws, size_t ws_size,
                              hipStream_t stream) {
  (void)in_sizes; (void)n_in; (void)out_size; (void)ws_size;
  const float* X = (const float*)d_in[0];
  const float* Wq = (const float*)d_in[1];
  const float* Wk = (const float*)d_in[2];
  const float* Wv = (const float*)d_in[3];
  const float* Wo = (const float*)d_in[4];

  char* ws = (char*)d_ws;
  unsigned short* Xbf  = (unsigned short*)(ws + 0);         // 4096x2048 (16MB)
  unsigned short* Wqkv = (unsigned short*)(ws + 16777216);  // 3072x2048 (12.6MB)
  unsigned short* Wob  = (unsigned short*)(ws + 29360128);  // 2048x2048 (8MB)
  unsigned short* Qraw = (unsigned short*)(ws + 37748736);  // 4096x2048 (16MB)
  unsigned short* Kraw = (unsigned short*)(ws + 54525952);  // 4096x512  (4MB)
  unsigned short* Vt   = (unsigned short*)(ws + 58720256);  // [b][kv][d][s] (4MB)
  float*          cosT = (float*)(ws + 62914560);           // 2048x64 f32 (512KB)
  float*          sinT = (float*)(ws + 63438848);           // 2048x64 f32 (512KB)
  unsigned short* Kr   = (unsigned short*)(ws + 79691776);  // [b][kv][s][d] (4MB)
  unsigned short* Ows  = (unsigned short*)(ws + 83886080);  // 4096x2048 (16MB)

  rope_table<<<512, 256, 0, stream>>>(cosT, sinT);
  cvt_kernel<<<8192, 256, 0, stream>>>(X, Xbf, 2097152);
  cvt_weights<<<10240, 256, 0, stream>>>(Wq, Wk, Wv, Wo, Wqkv, Wob);

  gemm2p<192, 2><<<256, 512, 0, stream>>>(Xbf, Wqkv, Qraw, Kraw, Vt);

  rope_k<<<4096, 256, 0, stream>>>(Kraw, Kr, cosT, sinT);

  attn_kernel<<<256, 512, 0, stream>>>(Qraw, Kr, Vt, Ows, cosT, sinT);

  gemm2p<128, 1><<<256, 512, 0, stream>>>(Ows, Wob, d_out, nullptr, nullptr);
}